// Round 11
// baseline (4069.535 us; speedup 1.0000x reference)
//
#include <hip/hip_runtime.h>
#include <hip/hip_bf16.h>
#include <math.h>

#define EPS 1e-5f
#define FL_SPLITS 5
#define FL_KEYS 500
#define GN_S 8

typedef __attribute__((ext_vector_type(8))) short short8;
typedef __attribute__((ext_vector_type(4))) float f4;

__device__ __forceinline__ short f2s(float f) {
    union { float f; unsigned u; } v; v.f = f;
    unsigned r = (v.u + 0x7fffu + ((v.u >> 16) & 1u)) >> 16;  // RNE
    return (short)r;
}

// ---------------- weight preprocessing ----------------
__global__ __launch_bounds__(256) void wcast_k(const float* __restrict__ in, short* __restrict__ out, int n)
{
    int i = blockIdx.x * 256 + threadIdx.x;
    if (i < n) out[i] = f2s(in[i]);
}

// (K,N) fp32 -> (N,K) bf16 ; blockIdx.z = matrix index
__global__ __launch_bounds__(256) void wtrans_k(const float* __restrict__ in, short* __restrict__ out,
                                                int K, int N)
{
    in  += (long)blockIdx.z * K * N;
    out += (long)blockIdx.z * K * N;
    __shared__ float t[64][65];
    int k0 = blockIdx.y * 64, n0 = blockIdx.x * 64;
    int tid = threadIdx.x;
    int cl = tid & 63, rq = tid >> 6;
    #pragma unroll
    for (int i = 0; i < 16; i++) {
        int rl = rq + i * 4;
        int k = k0 + rl, n = n0 + cl;
        t[rl][cl] = (k < K && n < N) ? in[(long)k * N + n] : 0.f;
    }
    __syncthreads();
    #pragma unroll
    for (int i = 0; i < 16; i++) {
        int nl = rq + i * 4;
        int n = n0 + nl, k = k0 + cl;
        if (n < N && k < K) out[(long)n * K + k] = f2s(t[cl][nl]);
    }
}

// ---------------- MFMA GEMM: C[M,N] = A(fp32 MxK) @ Bt(bf16 NxK)^T ----------------
__global__ __launch_bounds__(256) void mgemm_k(const float* __restrict__ A, int lda,
                                               const short* __restrict__ Bt,
                                               const float* __restrict__ bias,
                                               const float* __restrict__ resid,
                                               float* __restrict__ C,
                                               int M, int N, int K, int act)
{
    __shared__ __align__(16) short As[5120];   // 128 rows x 40 (32 used)
    __shared__ __align__(16) short Bs[5120];
    int tid = threadIdx.x;
    int wave = tid >> 6, lane = tid & 63;
    int wm = wave >> 1, wn = wave & 1;
    int quad = lane >> 4, l15 = lane & 15;
    int m0 = blockIdx.y * 128, n0 = blockIdx.x * 128;
    f4 acc[4][4];
    #pragma unroll
    for (int i = 0; i < 4; i++)
        #pragma unroll
        for (int j = 0; j < 4; j++)
            acc[i][j] = (f4){0.f, 0.f, 0.f, 0.f};
    for (int kt = 0; kt < K; kt += 32) {
        #pragma unroll
        for (int i = 0; i < 2; i++) {
            int u = tid + (i << 8);
            int row = u >> 2, kc = (u & 3) << 3;
            int gm = m0 + row;
            short8 pk = {0, 0, 0, 0, 0, 0, 0, 0};
            if (gm < M) {
                const float4* ap = (const float4*)(A + (long)gm * lda + kt + kc);
                float4 v0 = ap[0], v1 = ap[1];
                pk[0] = f2s(v0.x); pk[1] = f2s(v0.y); pk[2] = f2s(v0.z); pk[3] = f2s(v0.w);
                pk[4] = f2s(v1.x); pk[5] = f2s(v1.y); pk[6] = f2s(v1.z); pk[7] = f2s(v1.w);
            }
            *(short8*)&As[row * 40 + kc] = pk;
            int gn = n0 + row;
            short8 pb = {0, 0, 0, 0, 0, 0, 0, 0};
            if (gn < N) pb = *(const short8*)&Bt[(long)gn * K + kt + kc];
            *(short8*)&Bs[row * 40 + kc] = pb;
        }
        __syncthreads();
        short8 af[4], bf[4];
        #pragma unroll
        for (int mi = 0; mi < 4; mi++) af[mi] = *(const short8*)&As[(wm * 64 + mi * 16 + l15) * 40 + (quad << 3)];
        #pragma unroll
        for (int ni = 0; ni < 4; ni++) bf[ni] = *(const short8*)&Bs[(wn * 64 + ni * 16 + l15) * 40 + (quad << 3)];
        #pragma unroll
        for (int mi = 0; mi < 4; mi++)
            #pragma unroll
            for (int ni = 0; ni < 4; ni++)
                acc[mi][ni] = __builtin_amdgcn_mfma_f32_16x16x32_bf16(af[mi], bf[ni], acc[mi][ni], 0, 0, 0);
        __syncthreads();
    }
    #pragma unroll
    for (int mi = 0; mi < 4; mi++) {
        int row = m0 + wm * 64 + mi * 16 + quad * 4;
        #pragma unroll
        for (int ni = 0; ni < 4; ni++) {
            int col = n0 + wn * 64 + ni * 16 + l15;
            if (col >= N) continue;
            float bv = bias[col];
            #pragma unroll
            for (int r = 0; r < 4; r++) {
                int rr = row + r;
                if (rr >= M) continue;
                float v = acc[mi][ni][r] + bv;
                if (act == 2) v = 0.5f * v * (1.f + erff(v * 0.70710678118654752f));
                if (resid) v += resid[(long)rr * N + col];
                C[(long)rr * N + col] = v;
            }
        }
    }
}

// ---------------- MFMA conv 3x3 s2 p1: 128x64 tile, BK=32, register prefetch ----------------
// Input GN fused: coef = per-channel (scale,shift); v = relu(raw*sc+sh). Ktot % 32 == 0.
__global__ __launch_bounds__(256) void mconv_k(const float* __restrict__ in,   // (Cin,Hin,Win) raw
                                               const short* __restrict__ wgt,  // (Cout, Cin*9) bf16
                                               const float* __restrict__ coef, // (Cin,2) or null
                                               const float* __restrict__ bias,
                                               float* __restrict__ out,
                                               int Cin, int Cout, int Hin, int Win, int transout)
{
    const int Hout = Hin >> 1, Wout = Win >> 1;
    const int HWo = Hout * Wout;
    const int Ktot = Cin * 9;
    const int HW = Hin * Win;
    __shared__ __align__(16) short As[5120];   // 128 rows x 40
    __shared__ __align__(16) short Bs[2560];   // 64 cols x 40
    int tid = threadIdx.x;
    int wave = tid >> 6, lane = tid & 63;
    int wm = wave >> 1, wn = wave & 1;
    int quad = lane >> 4, l15 = lane & 15;
    int m0 = blockIdx.y * 128, n0 = blockIdx.x * 64;
    int nn = tid & 63;
    int kp0 = tid >> 6;
    int p = n0 + nn;
    int pok = p < HWo;
    int pc = pok ? p : (HWo - 1);
    int ho = pc / Wout, wo = pc - ho * Wout;
    int hb = ho * 2 - 1, wb = wo * 2 - 1;

    f4 acc[4][2];
    #pragma unroll
    for (int i = 0; i < 4; i++) { acc[i][0] = (f4){0.f,0.f,0.f,0.f}; acc[i][1] = (f4){0.f,0.f,0.f,0.f}; }

    short8 aR[2];
    float bR[4][2];
    auto loadA = [&](int kt) {
        #pragma unroll
        for (int i = 0; i < 2; i++) {
            int u = tid + (i << 8);
            int r = u >> 2, kc = (u & 3) << 3;
            aR[i] = *(const short8*)&wgt[(long)(m0 + r) * Ktot + kt + kc];
        }
    };
    auto gval = [&](int k) -> float {
        int ci = k / 9, r = k - ci * 9;
        int kh = r / 3, kw = r - kh * 3;
        int y = hb + kh, x = wb + kw;
        float v = 0.f;
        if (y >= 0 && y < Hin && x >= 0 && x < Win) {
            v = in[(long)ci * HW + y * Win + x];
            if (coef) v = fmaxf(fmaf(v, coef[ci * 2], coef[ci * 2 + 1]), 0.f);
        }
        return v;
    };
    auto loadB = [&](int kt) {
        #pragma unroll
        for (int i = 0; i < 4; i++) {
            int kp = kp0 + (i << 2);
            int k0 = kt + kp * 2;
            float lo = 0.f, hi = 0.f;
            if (pok) { lo = gval(k0); hi = gval(k0 + 1); }
            bR[i][0] = lo; bR[i][1] = hi;
        }
    };

    loadA(0); loadB(0);
    for (int kt = 0; kt < Ktot; kt += 32) {
        #pragma unroll
        for (int i = 0; i < 2; i++) {
            int u = tid + (i << 8);
            int r = u >> 2, kc = (u & 3) << 3;
            *(short8*)&As[r * 40 + kc] = aR[i];
        }
        #pragma unroll
        for (int i = 0; i < 4; i++) {
            int kp = kp0 + (i << 2);
            unsigned packed = (unsigned)(unsigned short)f2s(bR[i][0]) |
                              ((unsigned)(unsigned short)f2s(bR[i][1]) << 16);
            *(unsigned*)&Bs[nn * 40 + kp * 2] = packed;
        }
        __syncthreads();
        if (kt + 32 < Ktot) { loadA(kt + 32); loadB(kt + 32); }
        short8 af[4], bf[2];
        #pragma unroll
        for (int mi = 0; mi < 4; mi++) af[mi] = *(const short8*)&As[(wm * 64 + mi * 16 + l15) * 40 + (quad << 3)];
        #pragma unroll
        for (int ni = 0; ni < 2; ni++) bf[ni] = *(const short8*)&Bs[(wn * 32 + ni * 16 + l15) * 40 + (quad << 3)];
        #pragma unroll
        for (int mi = 0; mi < 4; mi++)
            #pragma unroll
            for (int ni = 0; ni < 2; ni++)
                acc[mi][ni] = __builtin_amdgcn_mfma_f32_16x16x32_bf16(af[mi], bf[ni], acc[mi][ni], 0, 0, 0);
        __syncthreads();
    }
    #pragma unroll
    for (int mi = 0; mi < 4; mi++) {
        int mbase = m0 + wm * 64 + mi * 16 + quad * 4;
        #pragma unroll
        for (int ni = 0; ni < 2; ni++) {
            int n = n0 + wn * 32 + ni * 16 + l15;
            if (n >= HWo) continue;
            #pragma unroll
            for (int r = 0; r < 4; r++) {
                int m = mbase + r;
                float v = acc[mi][ni][r] + bias[m];
                if (transout) out[(long)n * Cout + m] = v;
                else          out[(long)m * HWo + n] = v;
            }
        }
    }
}

// ---------------- conv0: direct fp32 implicit GEMM (K=27) ----------------
__global__ __launch_bounds__(256) void conv_gemm_k(const float* __restrict__ in,
                                                   const float* __restrict__ w,
                                                   const float* __restrict__ bias,
                                                   float* __restrict__ out,
                                                   int Cin, int Cout, int Hin, int Win)
{
    const int Hout = Hin >> 1, Wout = Win >> 1;
    const int HWo = Hout * Wout;
    const int Ktot = Cin * 9;
    __shared__ float As[16][68];
    __shared__ float Bs[16][68];
    int tid = threadIdx.x;
    int tx = tid & 15, ty = tid >> 4;
    int m0 = blockIdx.y * 64;
    int n0 = blockIdx.x * 64;
    int kb = tid >> 4;
    int nb = (tid & 15) * 4;
    int ma = tid >> 2;
    int ka0 = (tid & 3) * 4;
    int hibase[4], wibase[4], pmask[4];
    #pragma unroll
    for (int u = 0; u < 4; u++) {
        int p = n0 + nb + u;
        pmask[u] = p < HWo;
        int pc = pmask[u] ? p : (HWo - 1);
        int ho = pc / Wout, wo = pc - ho * Wout;
        hibase[u] = ho * 2 - 1;
        wibase[u] = wo * 2 - 1;
    }
    float acc[4][4] = {{0.f}};
    const long wrow = (long)(m0 + ma) * Ktot;
    for (int kt = 0; kt < Ktot; kt += 16) {
        #pragma unroll
        for (int u = 0; u < 4; u++) {
            int k = kt + ka0 + u;
            As[ka0 + u][ma] = (k < Ktot) ? w[wrow + k] : 0.f;
        }
        int k = kt + kb;
        float bvals[4] = {0.f, 0.f, 0.f, 0.f};
        if (k < Ktot) {
            int ci = k / 9, r = k - ci * 9;
            int kh = r / 3, kw = r - kh * 3;
            const float* ip = in + (long)ci * Hin * Win;
            #pragma unroll
            for (int u = 0; u < 4; u++) {
                int hi = hibase[u] + kh;
                int wi = wibase[u] + kw;
                if (pmask[u] && hi >= 0 && hi < Hin && wi >= 0 && wi < Win)
                    bvals[u] = ip[(long)hi * Win + wi];
            }
        }
        #pragma unroll
        for (int u = 0; u < 4; u++) Bs[kb][nb + u] = bvals[u];
        __syncthreads();
        #pragma unroll
        for (int kk = 0; kk < 16; kk++) {
            float av[4], bv[4];
            #pragma unroll
            for (int i = 0; i < 4; i++) av[i] = As[kk][ty * 4 + i];
            #pragma unroll
            for (int j = 0; j < 4; j++) bv[j] = Bs[kk][tx * 4 + j];
            #pragma unroll
            for (int i = 0; i < 4; i++)
                #pragma unroll
                for (int j = 0; j < 4; j++)
                    acc[i][j] += av[i] * bv[j];
        }
        __syncthreads();
    }
    #pragma unroll
    for (int i = 0; i < 4; i++) {
        int m = m0 + ty * 4 + i;
        float bb = bias[m];
        #pragma unroll
        for (int j = 0; j < 4; j++) {
            int n = n0 + tx * 4 + j;
            if (n < HWo) out[(long)m * HWo + n] = acc[i][j] + bb;
        }
    }
}

// ---------------- GroupNorm stats: partial sums, then per-channel (scale,shift) coef ----------------
__global__ __launch_bounds__(256) void gn_part_k(const float* __restrict__ x, long grpLen,
                                                 float* __restrict__ parts)
{
    int g = blockIdx.x, sp = blockIdx.y;
    long b0 = grpLen * sp / GN_S, b1 = grpLen * (sp + 1) / GN_S;
    const float* pbase = x + (long)g * grpLen;
    float s = 0.f, s2 = 0.f;
    for (long i = b0 + threadIdx.x; i < b1; i += 256) {
        float v = pbase[i];
        s += v; s2 += v * v;
    }
    __shared__ float rs[256], rq[256];
    rs[threadIdx.x] = s; rq[threadIdx.x] = s2;
    __syncthreads();
    for (int o = 128; o > 0; o >>= 1) {
        if (threadIdx.x < o) { rs[threadIdx.x] += rs[threadIdx.x + o]; rq[threadIdx.x] += rq[threadIdx.x + o]; }
        __syncthreads();
    }
    if (threadIdx.x == 0) {
        parts[(g * GN_S + sp) * 2]     = rs[0];
        parts[(g * GN_S + sp) * 2 + 1] = rq[0];
    }
}

// one block, C<=256 threads: coef[c] = (rstd*gamma, beta - mean*rstd*gamma)
__global__ __launch_bounds__(256) void gn_coef_k(const float* __restrict__ parts,
                                                 const float* __restrict__ gamma,
                                                 const float* __restrict__ beta,
                                                 float invN, int cpg, int C,
                                                 float* __restrict__ coef)
{
    int c = threadIdx.x;
    if (c >= C) return;
    int g = c / cpg;
    float s = 0.f, s2 = 0.f;
    #pragma unroll
    for (int i = 0; i < GN_S; i++) { s += parts[(g * GN_S + i) * 2]; s2 += parts[(g * GN_S + i) * 2 + 1]; }
    float mean = s * invN;
    float var  = s2 * invN - mean * mean;
    float rstd = rsqrtf(var + EPS);
    float sc = rstd * gamma[c];
    coef[c * 2]     = sc;
    coef[c * 2 + 1] = beta[c] - mean * sc;
}

// ---------------- GroupNorm for (1400 x 256) spatial-major, batched over cams (grid.y) ----------------
__global__ __launch_bounds__(256) void gn_stats_hwd_k(const float* __restrict__ x, float* __restrict__ stats)
{
    x += (long)blockIdx.y * 358400;
    stats += blockIdx.y * 64;
    int g = blockIdx.x;  // 32 groups
    float s = 0.f, s2 = 0.f;
    for (int i = threadIdx.x; i < 1400 * 8; i += blockDim.x) {
        int p = i >> 3, c = g * 8 + (i & 7);
        float v = x[(long)p * 256 + c];
        s += v; s2 += v * v;
    }
    __shared__ float rs[256], rq[256];
    rs[threadIdx.x] = s; rq[threadIdx.x] = s2;
    __syncthreads();
    for (int o = 128; o > 0; o >>= 1) {
        if (threadIdx.x < o) { rs[threadIdx.x] += rs[threadIdx.x + o]; rq[threadIdx.x] += rq[threadIdx.x + o]; }
        __syncthreads();
    }
    if (threadIdx.x == 0) {
        float mean = rs[0] / 11200.f;
        float var  = rq[0] / 11200.f - mean * mean;
        stats[g * 2]     = mean;
        stats[g * 2 + 1] = rsqrtf(var + EPS);
    }
}

__global__ __launch_bounds__(256) void gn_apply_hwd_k(float* __restrict__ x,
                                                      const float* __restrict__ gamma,
                                                      const float* __restrict__ beta,
                                                      const float* __restrict__ stats,
                                                      int relu)
{
    x += (long)blockIdx.y * 358400;
    stats += blockIdx.y * 64;
    int idx = blockIdx.x * 256 + threadIdx.x;  // 0..358399
    int c = idx & 255;
    int g = c >> 3;
    float v = (x[idx] - stats[g * 2]) * stats[g * 2 + 1] * gamma[c] + beta[c];
    if (relu) v = fmaxf(v, 0.f);
    x[idx] = v;
}

// ---------------- projection of BEV grid ----------------
__global__ __launch_bounds__(256) void project_k(const float* __restrict__ Kin,
                                                 const float* __restrict__ Ein,
                                                 float* __restrict__ refp, int* __restrict__ valid)
{
    int idx = blockIdx.x * blockDim.x + threadIdx.x;
    if (idx >= 2500 * 6) return;
    int c = idx % 6, q = idx / 6;
    int i = q / 50, j = q % 50;
    float px = (i - 24.5f) * 0.5f;
    float py = (j - 24.5f) * 0.5f;
    const float* E = Ein + c * 16;
    float pc[4];
    #pragma unroll
    for (int r = 0; r < 4; r++)
        pc[r] = E[r * 4 + 0] * px + E[r * 4 + 1] * py + E[r * 4 + 3];
    const float* Km = Kin + c * 9;
    float pix[3];
    #pragma unroll
    for (int r = 0; r < 3; r++)
        pix[r] = Km[r * 3 + 0] * pc[0] + Km[r * 3 + 1] * pc[1] + Km[r * 3 + 2] * pc[2];
    float z = fmaxf(pix[2], 1e-5f);
    float u = pix[0] / z, v = pix[1] / z;
    int ok = (pc[2] > 0.f) && (u >= 0.f) && (u < 800.f) && (v >= 0.f) && (v < 448.f);
    refp[(long)idx * 2 + 0] = 2.f * u / 799.f - 1.f;
    refp[(long)idx * 2 + 1] = 2.f * v / 447.f - 1.f;
    valid[idx] = ok;
}

// ---------------- misc elementwise ----------------
__global__ __launch_bounds__(256) void qinit_k(const float* __restrict__ a, const float* __restrict__ b,
                                               float* __restrict__ y)
{
    int i = blockIdx.x * blockDim.x + threadIdx.x;
    if (i >= 2500 * 256) return;
    y[i] = a[i] + b[i];
}

// ---------------- LayerNorm ----------------
__global__ __launch_bounds__(256) void ln_k(const float* __restrict__ x,
                                            const float* __restrict__ g, const float* __restrict__ b,
                                            float* __restrict__ y)
{
    int row  = blockIdx.x * 4 + (threadIdx.x >> 6);
    int lane = threadIdx.x & 63;
    if (row >= 2500) return;
    const float* xp = x + (long)row * 256;
    float v[4];
    #pragma unroll
    for (int i = 0; i < 4; i++) v[i] = xp[lane + 64 * i];
    float s  = v[0] + v[1] + v[2] + v[3];
    float s2 = v[0] * v[0] + v[1] * v[1] + v[2] * v[2] + v[3] * v[3];
    #pragma unroll
    for (int o = 32; o > 0; o >>= 1) { s += __shfl_xor(s, o, 64); s2 += __shfl_xor(s2, o, 64); }
    float mean = s * (1.f / 256.f);
    float var  = s2 * (1.f / 256.f) - mean * mean;
    float rstd = rsqrtf(var + EPS);
    #pragma unroll
    for (int i = 0; i < 4; i++) {
        int cc = lane + 64 * i;
        y[(long)row * 256 + cc] = (v[i] - mean) * rstd * g[cc] + b[cc];
    }
}

// ---------------- MFMA flash-2 MHA with split-K ----------------
__global__ __launch_bounds__(256) void flash2_k(const float* __restrict__ Q,
                                                const float* __restrict__ K,
                                                const float* __restrict__ V,
                                                float* __restrict__ Opart,   // (S,2500,256)
                                                float* __restrict__ MLpart)  // (S,2500,8,2)
{
    const int h  = blockIdx.y;
    const int q0 = blockIdx.x * 64;
    const int sp = blockIdx.z;
    const int kstart = sp * FL_KEYS, kend = kstart + FL_KEYS;
    const int tid = threadIdx.x;
    const int wave = tid >> 6, lane = tid & 63;
    const int quad = lane >> 4, l15 = lane & 15;
    __shared__ __align__(16) short Qs[64 * 40];
    __shared__ __align__(16) short Ks[64 * 40];
    __shared__ __align__(16) short Vt[32 * 72];
    __shared__ __align__(16) short Ps[64 * 72];
    const float scale = 0.17677669529663687f;
    {
        int row = tid >> 2, kc = (tid & 3) << 3;
        int qi = q0 + row;
        short8 pk = {0, 0, 0, 0, 0, 0, 0, 0};
        if (qi < 2500) {
            const float4* qp = (const float4*)(Q + (long)qi * 256 + h * 32 + kc);
            float4 v0 = qp[0], v1 = qp[1];
            pk[0] = f2s(v0.x * scale); pk[1] = f2s(v0.y * scale); pk[2] = f2s(v0.z * scale); pk[3] = f2s(v0.w * scale);
            pk[4] = f2s(v1.x * scale); pk[5] = f2s(v1.y * scale); pk[6] = f2s(v1.z * scale); pk[7] = f2s(v1.w * scale);
        }
        *(short8*)&Qs[row * 40 + kc] = pk;
    }
    __syncthreads();
    short8 aq = *(const short8*)&Qs[(wave * 16 + l15) * 40 + (quad << 3)];
    float m[4], l[4];
    f4 oacc[2];
    #pragma unroll
    for (int r = 0; r < 4; r++) { m[r] = -INFINITY; l[r] = 0.f; }
    oacc[0] = (f4){0.f, 0.f, 0.f, 0.f};
    oacc[1] = (f4){0.f, 0.f, 0.f, 0.f};
    for (int kb = kstart; kb < kend; kb += 64) {
        __syncthreads();
        {
            int row = tid >> 2, kc = (tid & 3) << 3;
            int ki = kb + row;
            short8 pk = {0, 0, 0, 0, 0, 0, 0, 0};
            float vv[8] = {0.f, 0.f, 0.f, 0.f, 0.f, 0.f, 0.f, 0.f};
            if (ki < kend) {
                const float4* kp = (const float4*)(K + (long)ki * 256 + h * 32 + kc);
                float4 a0 = kp[0], a1 = kp[1];
                pk[0] = f2s(a0.x); pk[1] = f2s(a0.y); pk[2] = f2s(a0.z); pk[3] = f2s(a0.w);
                pk[4] = f2s(a1.x); pk[5] = f2s(a1.y); pk[6] = f2s(a1.z); pk[7] = f2s(a1.w);
                const float4* vp = (const float4*)(V + (long)ki * 256 + h * 32 + kc);
                float4 b0 = vp[0], b1 = vp[1];
                vv[0] = b0.x; vv[1] = b0.y; vv[2] = b0.z; vv[3] = b0.w;
                vv[4] = b1.x; vv[5] = b1.y; vv[6] = b1.z; vv[7] = b1.w;
            }
            *(short8*)&Ks[row * 40 + kc] = pk;
            #pragma unroll
            for (int j = 0; j < 8; j++) Vt[(kc + j) * 72 + row] = f2s(vv[j]);
        }
        __syncthreads();
        f4 sa[4];
        #pragma unroll
        for (int ni = 0; ni < 4; ni++) {
            short8 bk = *(const short8*)&Ks[(ni * 16 + l15) * 40 + (quad << 3)];
            sa[ni] = __builtin_amdgcn_mfma_f32_16x16x32_bf16(aq, bk, (f4){0.f, 0.f, 0.f, 0.f}, 0, 0, 0);
        }
        float sv[4][4];
        #pragma unroll
        for (int ni = 0; ni < 4; ni++) {
            bool colok = (kb + ni * 16 + l15) < kend;
            #pragma unroll
            for (int r = 0; r < 4; r++) sv[ni][r] = colok ? sa[ni][r] : -1e30f;
        }
        float p[4][4];
        #pragma unroll
        for (int r = 0; r < 4; r++) {
            float rm = fmaxf(fmaxf(sv[0][r], sv[1][r]), fmaxf(sv[2][r], sv[3][r]));
            #pragma unroll
            for (int off = 1; off < 16; off <<= 1) rm = fmaxf(rm, __shfl_xor(rm, off, 16));
            float mn = fmaxf(m[r], rm);
            float alpha = __expf(m[r] - mn);
            float rs = 0.f;
            #pragma unroll
            for (int ni = 0; ni < 4; ni++) { p[ni][r] = __expf(sv[ni][r] - mn); rs += p[ni][r]; }
            #pragma unroll
            for (int off = 1; off < 16; off <<= 1) rs += __shfl_xor(rs, off, 16);
            l[r] = l[r] * alpha + rs;
            oacc[0][r] *= alpha; oacc[1][r] *= alpha;
            m[r] = mn;
        }
        #pragma unroll
        for (int ni = 0; ni < 4; ni++)
            #pragma unroll
            for (int r = 0; r < 4; r++)
                Ps[(wave * 16 + quad * 4 + r) * 72 + ni * 16 + l15] = f2s(p[ni][r]);
        #pragma unroll
        for (int kh = 0; kh < 2; kh++) {
            short8 ap = *(const short8*)&Ps[(wave * 16 + l15) * 72 + kh * 32 + (quad << 3)];
            #pragma unroll
            for (int ni = 0; ni < 2; ni++) {
                short8 bv = *(const short8*)&Vt[(ni * 16 + l15) * 72 + kh * 32 + (quad << 3)];
                oacc[ni] = __builtin_amdgcn_mfma_f32_16x16x32_bf16(ap, bv, oacc[ni], 0, 0, 0);
            }
        }
    }
    #pragma unroll
    for (int r = 0; r < 4; r++) {
        int qi = q0 + wave * 16 + quad * 4 + r;
        if (qi < 2500) {
            long ob = ((long)sp * 2500 + qi) * 256 + h * 32;
            Opart[ob + l15]      = oacc[0][r];
            Opart[ob + 16 + l15] = oacc[1][r];
            if (l15 == 0) {
                long mb = (((long)sp * 2500 + qi) * 8 + h) * 2;
                MLpart[mb]     = m[r];
                MLpart[mb + 1] = l[r];
            }
        }
    }
}

__global__ __launch_bounds__(256) void flashmerge_k(const float* __restrict__ Opart,
                                                    const float* __restrict__ MLpart,
                                                    float* __restrict__ O)
{
    int q = blockIdx.x, d = threadIdx.x;
    int h = d >> 5;
    float ms[FL_SPLITS], ls[FL_SPLITS];
    float mg = -INFINITY;
    #pragma unroll
    for (int s = 0; s < FL_SPLITS; s++) {
        long mb = (((long)s * 2500 + q) * 8 + h) * 2;
        ms[s] = MLpart[mb];
        ls[s] = MLpart[mb + 1];
        mg = fmaxf(mg, ms[s]);
    }
    float lsum = 0.f, osum = 0.f;
    #pragma unroll
    for (int s = 0; s < FL_SPLITS; s++) {
        float w = __expf(ms[s] - mg);
        lsum += ls[s] * w;
        osum += Opart[((long)s * 2500 + q) * 256 + d] * w;
    }
    O[(long)q * 256 + d] = osum / lsum;
}

// ---------------- masked softmax over 192 deformable-attn logits ----------------
__global__ __launch_bounds__(64) void scasoftmax_k(float* __restrict__ logits, const int* __restrict__ valid)
{
    int q = blockIdx.x, lane = threadIdx.x;
    float v[3]; int mk[3];
    #pragma unroll
    for (int i = 0; i < 3; i++) {
        int idx = i * 64 + lane;
        int c = idx >> 5;
        mk[i] = valid[q * 6 + c];
        v[i] = mk[i] ? logits[(long)q * 192 + idx] : -1e30f;
    }
    float mx = fmaxf(fmaxf(v[0], v[1]), v[2]);
    #pragma unroll
    for (int o = 32; o > 0; o >>= 1) mx = fmaxf(mx, __shfl_xor(mx, o, 64));
    float e[3]; float s = 0.f;
    #pragma unroll
    for (int i = 0; i < 3; i++) { e[i] = expf(v[i] - mx); s += e[i]; }
    #pragma unroll
    for (int o = 32; o > 0; o >>= 1) s += __shfl_xor(s, o, 64);
    float inv = 1.f / s;
    #pragma unroll
    for (int i = 0; i < 3; i++)
        logits[(long)q * 192 + i * 64 + lane] = mk[i] ? e[i] * inv : 0.f;
}

// ---------------- deformable sampling ----------------
__global__ __launch_bounds__(256) void sample_k(const float* __restrict__ vals,
                                                const float* __restrict__ offs,
                                                const float* __restrict__ wts,
                                                const float* __restrict__ refp,
                                                const int* __restrict__ valid,
                                                float* __restrict__ out)
{
    int q = blockIdx.x, d = threadIdx.x;
    __shared__ float s_cw[32][4];
    __shared__ int   s_idx[32][4];
    float acc = 0.f;
    for (int c = 0; c < 6; c++) {
        if (!valid[q * 6 + c]) continue;
        __syncthreads();
        if (d < 32) {
            float ox = offs[(long)q * 384 + (c * 32 + d) * 2 + 0];
            float oy = offs[(long)q * 384 + (c * 32 + d) * 2 + 1];
            float px = refp[(q * 6 + c) * 2 + 0] + ox * (2.f / 49.f);
            float py = refp[(q * 6 + c) * 2 + 1] + oy * (2.f / 27.f);
            float gx = (px + 1.f) * 0.5f * 49.f;
            float gy = (py + 1.f) * 0.5f * 27.f;
            float x0f = floorf(gx), y0f = floorf(gy);
            float wx = gx - x0f, wy = gy - y0f;
            int x0 = (int)x0f, y0 = (int)y0f;
            float wgt = wts[(long)q * 192 + c * 32 + d];
            float cw[4] = {(1.f - wx) * (1.f - wy), wx * (1.f - wy), (1.f - wx) * wy, wx * wy};
            const int dxs[4] = {0, 1, 0, 1};
            const int dys[4] = {0, 0, 1, 1};
            #pragma unroll
            for (int k2 = 0; k2 < 4; k2++) {
                int xi = x0 + dxs[k2], yi = y0 + dys[k2];
                bool ok = (xi >= 0) && (xi < 50) && (yi >= 0) && (yi < 28);
                s_cw[d][k2]  = ok ? cw[k2] * wgt : 0.f;
                s_idx[d][k2] = ok ? (yi * 50 + xi) * 256 : 0;
            }
        }
        __syncthreads();
        const float* vb = vals + (long)c * 358400 + d;
        for (int pt = 0; pt < 32; pt++) {
            #pragma unroll
            for (int k2 = 0; k2 < 4; k2++) {
                float cwv = s_cw[pt][k2];
                if (cwv != 0.f) acc += cwv * vb[s_idx[pt][k2]];
            }
        }
    }
    out[(long)q * 256 + d] = acc;
}

// =====================================================================================
extern "C" void kernel_launch(void* const* d_in, const int* in_sizes, int n_in,
                              void* d_out, int out_size, void* d_ws, size_t ws_size,
                              hipStream_t stream)
{
    const float* images = (const float*)d_in[0];
    const float* intr   = (const float*)d_in[1];
    const float* e2c    = (const float*)d_in[2];
    const float* bevq   = (const float*)d_in[3];
    const float* bevp   = (const float*)d_in[4];
    const float* bbw[5]    = {(const float*)d_in[5],  (const float*)d_in[9],  (const float*)d_in[13], (const float*)d_in[17], (const float*)d_in[21]};
    const float* bbb[5]    = {(const float*)d_in[6],  (const float*)d_in[10], (const float*)d_in[14], (const float*)d_in[18], (const float*)d_in[22]};
    const float* bbg[5]    = {(const float*)d_in[7],  (const float*)d_in[11], (const float*)d_in[15], (const float*)d_in[19], (const float*)d_in[23]};
    const float* bbbeta[5] = {(const float*)d_in[8],  (const float*)d_in[12], (const float*)d_in[16], (const float*)d_in[20], (const float*)d_in[24]};
    const float* sa_wq = (const float*)d_in[25]; const float* sa_bq = (const float*)d_in[26];
    const float* sa_wk = (const float*)d_in[27]; const float* sa_bk = (const float*)d_in[28];
    const float* sa_wv = (const float*)d_in[29]; const float* sa_bv = (const float*)d_in[30];
    const float* sa_wo = (const float*)d_in[31]; const float* sa_bo = (const float*)d_in[32];
    const float* ln1g = (const float*)d_in[33]; const float* ln1b = (const float*)d_in[34];
    const float* ln2g = (const float*)d_in[35]; const float* ln2b = (const float*)d_in[36];
    const float* ln3g = (const float*)d_in[37]; const float* ln3b = (const float*)d_in[38];
    const float* offw = (const float*)d_in[39]; const float* offb = (const float*)d_in[40];
    const float* wtw  = (const float*)d_in[41]; const float* wtb  = (const float*)d_in[42];
    const float* valw = (const float*)d_in[43]; const float* valb = (const float*)d_in[44];
    const float* outw = (const float*)d_in[45]; const float* outb = (const float*)d_in[46];
    const float* fw1  = (const float*)d_in[47]; const float* fb1  = (const float*)d_in[48];
    const float* fw2  = (const float*)d_in[49]; const float* fb2  = (const float*)d_in[50];

    // ---- workspace: ~77.0 MB ----
    float* ws = (float*)d_ws;
    float* bbA   = ws;            ws += 5734400;   // conv0 out / flash Opart (3.2M) + valsb alias
    float* bbB   = ws;            ws += 2867200;   // conv1 out / flash MLpart
    float* feats = ws;            ws += 2150400;   // (6,1400,256) hwd
    float* qbuf  = ws;            ws += 640000;
    float* xq    = ws;            ws += 640000;
    float* bQ    = ws;            ws += 640000;
    float* bK    = ws;            ws += 640000;
    float* bV    = ws;            ws += 640000;
    float* bO    = ws;            ws += 640000;
    float* bH    = ws;            ws += 2560000;   // ffn hidden / offsets / conv3-out (feats3)
    float* bW    = ws;            ws += 480000;    // logits/weights (2500,192)
    float* refp  = ws;            ws += 30016;
    int*   validb = (int*)ws;     ws += 15040;
    float* stats = ws;            ws += 384;       // 6 cams x 32 groups x 2
    float* parts = ws;            ws += 512;       // 32 groups x GN_S x 2
    float* coef  = ws;            ws += 512;       // per-channel (scale,shift), up to 256 ch
    // aliases
    float* valsb  = bbA + 3200000;
    float* feats3 = bH;
    // bf16 weight buffers
    short* sb = (short*)ws;
    short* cw1b = sb; sb += 73728;
    short* cw2b = sb; sb += 294912;
    short* cw3b = sb; sb += 589824;
    short* cw4b = sb; sb += 65536;
    short* qwT  = sb; sb += 131072;
    short* kwT  = sb; sb += 131072;
    short* vwT  = sb; sb += 131072;
    short* owT  = sb; sb += 131072;
    short* valT = sb; sb += 131072;
    short* outT = sb; sb += 131072;
    short* offT = sb; sb += 196608;
    short* wtT  = sb; sb += 98304;
    short* f1T  = sb; sb += 524288;
    short* f2T  = sb; sb += 524288;

    auto mgemm = [&](const float* A, int lda, const short* Bt, const float* bias, const float* resid,
                     float* C, int M, int N, int K, int act) {
        dim3 g((N + 127) / 128, (M + 127) / 128);
        mgemm_k<<<g, 256, 0, stream>>>(A, lda, Bt, bias, resid, C, M, N, K, act);
    };

    // ---- weight preprocessing ----
    wcast_k<<<(73728 + 255) / 256, 256, 0, stream>>>(bbw[1], cw1b, 73728);
    wcast_k<<<(294912 + 255) / 256, 256, 0, stream>>>(bbw[2], cw2b, 294912);
    wcast_k<<<(589824 + 255) / 256, 256, 0, stream>>>(bbw[3], cw3b, 589824);
    wcast_k<<<(65536 + 255) / 256, 256, 0, stream>>>(bbw[4], cw4b, 65536);
    wtrans_k<<<dim3(4, 4, 2), 256, 0, stream>>>(sa_wq, qwT, 256, 256);
    wtrans_k<<<dim3(4, 4, 2), 256, 0, stream>>>(sa_wk, kwT, 256, 256);
    wtrans_k<<<dim3(4, 4, 2), 256, 0, stream>>>(sa_wv, vwT, 256, 256);
    wtrans_k<<<dim3(4, 4, 2), 256, 0, stream>>>(sa_wo, owT, 256, 256);
    wtrans_k<<<dim3(4, 4, 2), 256, 0, stream>>>(valw, valT, 256, 256);
    wtrans_k<<<dim3(4, 4, 2), 256, 0, stream>>>(outw, outT, 256, 256);
    wtrans_k<<<dim3(6, 4, 2), 256, 0, stream>>>(offw, offT, 256, 384);
    wtrans_k<<<dim3(3, 4, 2), 256, 0, stream>>>(wtw, wtT, 256, 192);
    wtrans_k<<<dim3(16, 4, 2), 256, 0, stream>>>(fw1, f1T, 256, 1024);
    wtrans_k<<<dim3(4, 16, 2), 256, 0, stream>>>(fw2, f2T, 1024, 256);

    // ---- projection of BEV grid ----
    project_k<<<(15000 + 255) / 256, 256, 0, stream>>>(intr, e2c, refp, validb);

    // ---- backbone (GN of conv0..conv2 fused into next conv's gather) ----
    for (int c = 0; c < 6; c++) {
        const float* img = images + (long)c * 3 * 448 * 800;
        conv_gemm_k<<<dim3(1400, 1), 256, 0, stream>>>(img, bbw[0], bbb[0], bbA, 3, 64, 448, 800);
        gn_part_k<<<dim3(32, GN_S), 256, 0, stream>>>(bbA, 179200L, parts);
        gn_coef_k<<<1, 256, 0, stream>>>(parts, bbg[0], bbbeta[0], 1.f / 179200.f, 2, 64, coef);

        mconv_k<<<dim3(350, 1), 256, 0, stream>>>(bbA, cw1b, coef, bbb[1], bbB, 64, 128, 224, 400, 0);
        gn_part_k<<<dim3(32, GN_S), 256, 0, stream>>>(bbB, 89600L, parts);
        gn_coef_k<<<1, 256, 0, stream>>>(parts, bbg[1], bbbeta[1], 1.f / 89600.f, 4, 128, coef);

        mconv_k<<<dim3(88, 2), 256, 0, stream>>>(bbB, cw2b, coef, bbb[2], bbA, 128, 256, 112, 200, 0);
        gn_part_k<<<dim3(32, GN_S), 256, 0, stream>>>(bbA, 44800L, parts);
        gn_coef_k<<<1, 256, 0, stream>>>(parts, bbg[2], bbbeta[2], 1.f / 44800.f, 8, 256, coef);

        // conv3 (GN2 fused on input) writes spatial-major raw into feats3[c]
        mconv_k<<<dim3(22, 2), 256, 0, stream>>>(bbA, cw3b, coef, bbb[3], feats3 + (long)c * 358400, 256, 256, 56, 100, 1);
    }
    // batched conv3-GN (+relu), conv4 as one 8400x256 GEMM, batched conv4-GN
    gn_stats_hwd_k<<<dim3(32, 6), 256, 0, stream>>>(feats3, stats);
    gn_apply_hwd_k<<<dim3(1400, 6), 256, 0, stream>>>(feats3, bbg[3], bbbeta[3], stats, 1);
    mgemm(feats3, 256, cw4b, bbb[4], nullptr, feats, 8400, 256, 256, 0);
    gn_stats_hwd_k<<<dim3(32, 6), 256, 0, stream>>>(feats, stats);
    gn_apply_hwd_k<<<dim3(1400, 6), 256, 0, stream>>>(feats, bbg[4], bbbeta[4], stats, 0);

    // ---- transformer ----
    qinit_k<<<2500, 256, 0, stream>>>(bevq, bevp, qbuf);

    for (int l = 0; l < 2; l++) {
        long o1 = (long)l * 256;

        // self-attention
        ln_k<<<625, 256, 0, stream>>>(qbuf, ln1g + o1, ln1b + o1, xq);
        mgemm(xq, 256, qwT + l * 65536, sa_bq + o1, nullptr, bQ, 2500, 256, 256, 0);
        mgemm(xq, 256, kwT + l * 65536, sa_bk + o1, nullptr, bK, 2500, 256, 256, 0);
        mgemm(xq, 256, vwT + l * 65536, sa_bv + o1, nullptr, bV, 2500, 256, 256, 0);
        flash2_k<<<dim3(40, 8, FL_SPLITS), 256, 0, stream>>>(bQ, bK, bV, bbA, bbB);
        flashmerge_k<<<2500, 256, 0, stream>>>(bbA, bbB, bO);
        mgemm(bO, 256, owT + l * 65536, sa_bo + o1, qbuf, qbuf, 2500, 256, 256, 0);

        // spatial cross-attention
        ln_k<<<625, 256, 0, stream>>>(qbuf, ln2g + o1, ln2b + o1, xq);
        mgemm(feats, 256, valT + l * 65536, valb + o1, nullptr, valsb, 8400, 256, 256, 0);
        mgemm(xq, 256, offT + l * 98304, offb + (long)l * 384, nullptr, bH, 2500, 384, 256, 0);
        mgemm(xq, 256, wtT + l * 49152, wtb + (long)l * 192, nullptr, bW, 2500, 192, 256, 0);
        scasoftmax_k<<<2500, 64, 0, stream>>>(bW, validb);
        sample_k<<<2500, 256, 0, stream>>>(valsb, bH, bW, refp, validb, bO);
        mgemm(bO, 256, outT + l * 65536, outb + o1, qbuf, qbuf, 2500, 256, 256, 0);

        // FFN
        ln_k<<<625, 256, 0, stream>>>(qbuf, ln3g + o1, ln3b + o1, xq);
        mgemm(xq, 256, f1T + l * 262144, fb1 + (long)l * 1024, nullptr, bH, 2500, 1024, 256, 2);
        mgemm(bH, 1024, f2T + l * 262144, fb2 + o1, qbuf,
              (l == 1) ? (float*)d_out : qbuf, 2500, 256, 1024, 0);
    }
}

// Round 12
// 3012.728 us; speedup vs baseline: 1.3508x; 1.3508x over previous
//
#include <hip/hip_runtime.h>
#include <hip/hip_bf16.h>
#include <math.h>

#define EPS 1e-5f
#define FL_SPLITS 5
#define FL_KEYS 500
#define GN_S 8

typedef __attribute__((ext_vector_type(8))) short short8;
typedef __attribute__((ext_vector_type(4))) float f4;

__device__ __forceinline__ short f2s(float f) {
    union { float f; unsigned u; } v; v.f = f;
    unsigned r = (v.u + 0x7fffu + ((v.u >> 16) & 1u)) >> 16;  // RNE
    return (short)r;
}

// ---------------- weight preprocessing ----------------
__global__ __launch_bounds__(256) void wcast_k(const float* __restrict__ in, short* __restrict__ out, int n)
{
    int i = blockIdx.x * 256 + threadIdx.x;
    if (i < n) out[i] = f2s(in[i]);
}

// (K,N) fp32 -> (N,K) bf16 ; blockIdx.z = matrix index
__global__ __launch_bounds__(256) void wtrans_k(const float* __restrict__ in, short* __restrict__ out,
                                                int K, int N)
{
    in  += (long)blockIdx.z * K * N;
    out += (long)blockIdx.z * K * N;
    __shared__ float t[64][65];
    int k0 = blockIdx.y * 64, n0 = blockIdx.x * 64;
    int tid = threadIdx.x;
    int cl = tid & 63, rq = tid >> 6;
    #pragma unroll
    for (int i = 0; i < 16; i++) {
        int rl = rq + i * 4;
        int k = k0 + rl, n = n0 + cl;
        t[rl][cl] = (k < K && n < N) ? in[(long)k * N + n] : 0.f;
    }
    __syncthreads();
    #pragma unroll
    for (int i = 0; i < 16; i++) {
        int nl = rq + i * 4;
        int n = n0 + nl, k = k0 + cl;
        if (n < N && k < K) out[(long)n * K + k] = f2s(t[cl][nl]);
    }
}

// ---------------- MFMA GEMM: C[M,N] = A(fp32 MxK) @ Bt(bf16 NxK)^T ----------------
__global__ __launch_bounds__(256) void mgemm_k(const float* __restrict__ A, int lda,
                                               const short* __restrict__ Bt,
                                               const float* __restrict__ bias,
                                               const float* __restrict__ resid,
                                               float* __restrict__ C,
                                               int M, int N, int K, int act)
{
    __shared__ __align__(16) short As[5120];   // 128 rows x 40 (32 used)
    __shared__ __align__(16) short Bs[5120];
    int tid = threadIdx.x;
    int wave = tid >> 6, lane = tid & 63;
    int wm = wave >> 1, wn = wave & 1;
    int quad = lane >> 4, l15 = lane & 15;
    int m0 = blockIdx.y * 128, n0 = blockIdx.x * 128;
    f4 acc[4][4];
    #pragma unroll
    for (int i = 0; i < 4; i++)
        #pragma unroll
        for (int j = 0; j < 4; j++)
            acc[i][j] = (f4){0.f, 0.f, 0.f, 0.f};
    for (int kt = 0; kt < K; kt += 32) {
        #pragma unroll
        for (int i = 0; i < 2; i++) {
            int u = tid + (i << 8);
            int row = u >> 2, kc = (u & 3) << 3;
            int gm = m0 + row;
            short8 pk = {0, 0, 0, 0, 0, 0, 0, 0};
            if (gm < M) {
                const float4* ap = (const float4*)(A + (long)gm * lda + kt + kc);
                float4 v0 = ap[0], v1 = ap[1];
                pk[0] = f2s(v0.x); pk[1] = f2s(v0.y); pk[2] = f2s(v0.z); pk[3] = f2s(v0.w);
                pk[4] = f2s(v1.x); pk[5] = f2s(v1.y); pk[6] = f2s(v1.z); pk[7] = f2s(v1.w);
            }
            *(short8*)&As[row * 40 + kc] = pk;
            int gn = n0 + row;
            short8 pb = {0, 0, 0, 0, 0, 0, 0, 0};
            if (gn < N) pb = *(const short8*)&Bt[(long)gn * K + kt + kc];
            *(short8*)&Bs[row * 40 + kc] = pb;
        }
        __syncthreads();
        short8 af[4], bf[4];
        #pragma unroll
        for (int mi = 0; mi < 4; mi++) af[mi] = *(const short8*)&As[(wm * 64 + mi * 16 + l15) * 40 + (quad << 3)];
        #pragma unroll
        for (int ni = 0; ni < 4; ni++) bf[ni] = *(const short8*)&Bs[(wn * 64 + ni * 16 + l15) * 40 + (quad << 3)];
        #pragma unroll
        for (int mi = 0; mi < 4; mi++)
            #pragma unroll
            for (int ni = 0; ni < 4; ni++)
                acc[mi][ni] = __builtin_amdgcn_mfma_f32_16x16x32_bf16(af[mi], bf[ni], acc[mi][ni], 0, 0, 0);
        __syncthreads();
    }
    #pragma unroll
    for (int mi = 0; mi < 4; mi++) {
        int row = m0 + wm * 64 + mi * 16 + quad * 4;
        #pragma unroll
        for (int ni = 0; ni < 4; ni++) {
            int col = n0 + wn * 64 + ni * 16 + l15;
            if (col >= N) continue;
            float bv = bias[col];
            #pragma unroll
            for (int r = 0; r < 4; r++) {
                int rr = row + r;
                if (rr >= M) continue;
                float v = acc[mi][ni][r] + bv;
                if (act == 2) v = 0.5f * v * (1.f + erff(v * 0.70710678118654752f));
                if (resid) v += resid[(long)rr * N + col];
                C[(long)rr * N + col] = v;
            }
        }
    }
}

// ---------------- MFMA conv 3x3 s2 p1: 64x64 tile, BK=32, register prefetch ----------------
// Ktot % 32 == 0. No input fusion (GN applied separately — measured faster, r11).
__global__ __launch_bounds__(256) void mconv_k(const float* __restrict__ in,   // (Cin,Hin,Win)
                                               const short* __restrict__ wgt,  // (Cout, Cin*9) bf16
                                               const float* __restrict__ bias,
                                               float* __restrict__ out,
                                               int Cin, int Cout, int Hin, int Win, int transout)
{
    const int Hout = Hin >> 1, Wout = Win >> 1;
    const int HWo = Hout * Wout;
    const int Ktot = Cin * 9;
    const int HW = Hin * Win;
    __shared__ __align__(16) short As[2560];   // 64 rows x 40
    __shared__ __align__(16) short Bs[2560];   // 64 cols x 40
    int tid = threadIdx.x;
    int wave = tid >> 6, lane = tid & 63;
    int wm = wave >> 1, wn = wave & 1;         // wave covers rows wm*32.., cols wn*32..
    int quad = lane >> 4, l15 = lane & 15;
    int m0 = blockIdx.y * 64, n0 = blockIdx.x * 64;
    int nn = tid & 63;
    int kp0 = tid >> 6;
    int p = n0 + nn;
    int pok = p < HWo;
    int pc = pok ? p : (HWo - 1);
    int ho = pc / Wout, wo = pc - ho * Wout;
    int hb = ho * 2 - 1, wb = wo * 2 - 1;

    f4 acc[2][2];
    #pragma unroll
    for (int i = 0; i < 2; i++) { acc[i][0] = (f4){0.f,0.f,0.f,0.f}; acc[i][1] = (f4){0.f,0.f,0.f,0.f}; }

    short8 aR;
    float bR[4][2];
    auto loadA = [&](int kt) {
        int r = tid >> 2, kc = (tid & 3) << 3;
        aR = *(const short8*)&wgt[(long)(m0 + r) * Ktot + kt + kc];
    };
    auto loadB = [&](int kt) {
        #pragma unroll
        for (int i = 0; i < 4; i++) {
            int kp = kp0 + (i << 2);
            int k0 = kt + kp * 2;
            float lo = 0.f, hi = 0.f;
            if (pok) {
                int ci = k0 / 9, r = k0 - ci * 9;
                int kh = r / 3, kw = r - kh * 3;
                int y = hb + kh, x = wb + kw;
                if (y >= 0 && y < Hin && x >= 0 && x < Win) lo = in[(long)ci * HW + y * Win + x];
                int k1 = k0 + 1;
                ci = k1 / 9; r = k1 - ci * 9; kh = r / 3; kw = r - kh * 3;
                y = hb + kh; x = wb + kw;
                if (y >= 0 && y < Hin && x >= 0 && x < Win) hi = in[(long)ci * HW + y * Win + x];
            }
            bR[i][0] = lo; bR[i][1] = hi;
        }
    };

    loadA(0); loadB(0);
    for (int kt = 0; kt < Ktot; kt += 32) {
        {
            int r = tid >> 2, kc = (tid & 3) << 3;
            *(short8*)&As[r * 40 + kc] = aR;
        }
        #pragma unroll
        for (int i = 0; i < 4; i++) {
            int kp = kp0 + (i << 2);
            unsigned packed = (unsigned)(unsigned short)f2s(bR[i][0]) |
                              ((unsigned)(unsigned short)f2s(bR[i][1]) << 16);
            *(unsigned*)&Bs[nn * 40 + kp * 2] = packed;
        }
        __syncthreads();
        if (kt + 32 < Ktot) { loadA(kt + 32); loadB(kt + 32); }
        short8 af[2], bf[2];
        #pragma unroll
        for (int mi = 0; mi < 2; mi++) af[mi] = *(const short8*)&As[(wm * 32 + mi * 16 + l15) * 40 + (quad << 3)];
        #pragma unroll
        for (int ni = 0; ni < 2; ni++) bf[ni] = *(const short8*)&Bs[(wn * 32 + ni * 16 + l15) * 40 + (quad << 3)];
        #pragma unroll
        for (int mi = 0; mi < 2; mi++)
            #pragma unroll
            for (int ni = 0; ni < 2; ni++)
                acc[mi][ni] = __builtin_amdgcn_mfma_f32_16x16x32_bf16(af[mi], bf[ni], acc[mi][ni], 0, 0, 0);
        __syncthreads();
    }
    #pragma unroll
    for (int mi = 0; mi < 2; mi++) {
        int mbase = m0 + wm * 32 + mi * 16 + quad * 4;
        #pragma unroll
        for (int ni = 0; ni < 2; ni++) {
            int n = n0 + wn * 32 + ni * 16 + l15;
            if (n >= HWo) continue;
            #pragma unroll
            for (int r = 0; r < 4; r++) {
                int m = mbase + r;
                float v = acc[mi][ni][r] + bias[m];
                if (transout) out[(long)n * Cout + m] = v;
                else          out[(long)m * HWo + n] = v;
            }
        }
    }
}

// ---------------- conv0: direct fp32 implicit GEMM (K=27) ----------------
__global__ __launch_bounds__(256) void conv_gemm_k(const float* __restrict__ in,
                                                   const float* __restrict__ w,
                                                   const float* __restrict__ bias,
                                                   float* __restrict__ out,
                                                   int Cin, int Cout, int Hin, int Win)
{
    const int Hout = Hin >> 1, Wout = Win >> 1;
    const int HWo = Hout * Wout;
    const int Ktot = Cin * 9;
    __shared__ float As[16][68];
    __shared__ float Bs[16][68];
    int tid = threadIdx.x;
    int tx = tid & 15, ty = tid >> 4;
    int m0 = blockIdx.y * 64;
    int n0 = blockIdx.x * 64;
    int kb = tid >> 4;
    int nb = (tid & 15) * 4;
    int ma = tid >> 2;
    int ka0 = (tid & 3) * 4;
    int hibase[4], wibase[4], pmask[4];
    #pragma unroll
    for (int u = 0; u < 4; u++) {
        int p = n0 + nb + u;
        pmask[u] = p < HWo;
        int pc = pmask[u] ? p : (HWo - 1);
        int ho = pc / Wout, wo = pc - ho * Wout;
        hibase[u] = ho * 2 - 1;
        wibase[u] = wo * 2 - 1;
    }
    float acc[4][4] = {{0.f}};
    const long wrow = (long)(m0 + ma) * Ktot;
    for (int kt = 0; kt < Ktot; kt += 16) {
        #pragma unroll
        for (int u = 0; u < 4; u++) {
            int k = kt + ka0 + u;
            As[ka0 + u][ma] = (k < Ktot) ? w[wrow + k] : 0.f;
        }
        int k = kt + kb;
        float bvals[4] = {0.f, 0.f, 0.f, 0.f};
        if (k < Ktot) {
            int ci = k / 9, r = k - ci * 9;
            int kh = r / 3, kw = r - kh * 3;
            const float* ip = in + (long)ci * Hin * Win;
            #pragma unroll
            for (int u = 0; u < 4; u++) {
                int hi = hibase[u] + kh;
                int wi = wibase[u] + kw;
                if (pmask[u] && hi >= 0 && hi < Hin && wi >= 0 && wi < Win)
                    bvals[u] = ip[(long)hi * Win + wi];
            }
        }
        #pragma unroll
        for (int u = 0; u < 4; u++) Bs[kb][nb + u] = bvals[u];
        __syncthreads();
        #pragma unroll
        for (int kk = 0; kk < 16; kk++) {
            float av[4], bv[4];
            #pragma unroll
            for (int i = 0; i < 4; i++) av[i] = As[kk][ty * 4 + i];
            #pragma unroll
            for (int j = 0; j < 4; j++) bv[j] = Bs[kk][tx * 4 + j];
            #pragma unroll
            for (int i = 0; i < 4; i++)
                #pragma unroll
                for (int j = 0; j < 4; j++)
                    acc[i][j] += av[i] * bv[j];
        }
        __syncthreads();
    }
    #pragma unroll
    for (int i = 0; i < 4; i++) {
        int m = m0 + ty * 4 + i;
        float bb = bias[m];
        #pragma unroll
        for (int j = 0; j < 4; j++) {
            int n = n0 + tx * 4 + j;
            if (n < HWo) out[(long)m * HWo + n] = acc[i][j] + bb;
        }
    }
}

// ---------------- GroupNorm two-stage; apply folds the final reduction ----------------
__global__ __launch_bounds__(256) void gn_part_k(const float* __restrict__ x, long grpLen,
                                                 float* __restrict__ parts)
{
    int g = blockIdx.x, sp = blockIdx.y;
    long b0 = grpLen * sp / GN_S, b1 = grpLen * (sp + 1) / GN_S;
    const float* pbase = x + (long)g * grpLen;
    float s = 0.f, s2 = 0.f;
    for (long i = b0 + threadIdx.x; i < b1; i += 256) {
        float v = pbase[i];
        s += v; s2 += v * v;
    }
    __shared__ float rs[256], rq[256];
    rs[threadIdx.x] = s; rq[threadIdx.x] = s2;
    __syncthreads();
    for (int o = 128; o > 0; o >>= 1) {
        if (threadIdx.x < o) { rs[threadIdx.x] += rs[threadIdx.x + o]; rq[threadIdx.x] += rq[threadIdx.x + o]; }
        __syncthreads();
    }
    if (threadIdx.x == 0) {
        parts[(g * GN_S + sp) * 2]     = rs[0];
        parts[(g * GN_S + sp) * 2 + 1] = rq[0];
    }
}

__global__ __launch_bounds__(256) void gn_apply_k(float* __restrict__ x,
                                                  const float* __restrict__ gamma,
                                                  const float* __restrict__ beta,
                                                  const float* __restrict__ parts, float invN,
                                                  int HW, int cpg, int total, int relu)
{
    __shared__ float smean[32], srstd[32];
    int t = threadIdx.x;
    if (t < 32) {
        float s = 0.f, s2 = 0.f;
        #pragma unroll
        for (int i = 0; i < GN_S; i++) { s += parts[(t * GN_S + i) * 2]; s2 += parts[(t * GN_S + i) * 2 + 1]; }
        float mean = s * invN;
        float var  = s2 * invN - mean * mean;
        smean[t] = mean; srstd[t] = rsqrtf(var + EPS);
    }
    __syncthreads();
    int idx = blockIdx.x * 256 + t;
    if (idx >= total) return;
    int c = idx / HW;
    int g = c / cpg;
    float v = (x[idx] - smean[g]) * srstd[g] * gamma[c] + beta[c];
    if (relu) v = fmaxf(v, 0.f);
    x[idx] = v;
}

// ---------------- GroupNorm for (1400 x 256) spatial-major, batched over cams (grid.y) ----------------
__global__ __launch_bounds__(256) void gn_stats_hwd_k(const float* __restrict__ x, float* __restrict__ stats)
{
    x += (long)blockIdx.y * 358400;
    stats += blockIdx.y * 64;
    int g = blockIdx.x;  // 32 groups
    float s = 0.f, s2 = 0.f;
    for (int i = threadIdx.x; i < 1400 * 8; i += blockDim.x) {
        int p = i >> 3, c = g * 8 + (i & 7);
        float v = x[(long)p * 256 + c];
        s += v; s2 += v * v;
    }
    __shared__ float rs[256], rq[256];
    rs[threadIdx.x] = s; rq[threadIdx.x] = s2;
    __syncthreads();
    for (int o = 128; o > 0; o >>= 1) {
        if (threadIdx.x < o) { rs[threadIdx.x] += rs[threadIdx.x + o]; rq[threadIdx.x] += rq[threadIdx.x + o]; }
        __syncthreads();
    }
    if (threadIdx.x == 0) {
        float mean = rs[0] / 11200.f;
        float var  = rq[0] / 11200.f - mean * mean;
        stats[g * 2]     = mean;
        stats[g * 2 + 1] = rsqrtf(var + EPS);
    }
}

__global__ __launch_bounds__(256) void gn_apply_hwd_k(float* __restrict__ x,
                                                      const float* __restrict__ gamma,
                                                      const float* __restrict__ beta,
                                                      const float* __restrict__ stats,
                                                      int relu)
{
    x += (long)blockIdx.y * 358400;
    stats += blockIdx.y * 64;
    int idx = blockIdx.x * 256 + threadIdx.x;  // 0..358399
    int c = idx & 255;
    int g = c >> 3;
    float v = (x[idx] - stats[g * 2]) * stats[g * 2 + 1] * gamma[c] + beta[c];
    if (relu) v = fmaxf(v, 0.f);
    x[idx] = v;
}

// ---------------- projection of BEV grid ----------------
__global__ __launch_bounds__(256) void project_k(const float* __restrict__ Kin,
                                                 const float* __restrict__ Ein,
                                                 float* __restrict__ refp, int* __restrict__ valid)
{
    int idx = blockIdx.x * blockDim.x + threadIdx.x;
    if (idx >= 2500 * 6) return;
    int c = idx % 6, q = idx / 6;
    int i = q / 50, j = q % 50;
    float px = (i - 24.5f) * 0.5f;
    float py = (j - 24.5f) * 0.5f;
    const float* E = Ein + c * 16;
    float pc[4];
    #pragma unroll
    for (int r = 0; r < 4; r++)
        pc[r] = E[r * 4 + 0] * px + E[r * 4 + 1] * py + E[r * 4 + 3];
    const float* Km = Kin + c * 9;
    float pix[3];
    #pragma unroll
    for (int r = 0; r < 3; r++)
        pix[r] = Km[r * 3 + 0] * pc[0] + Km[r * 3 + 1] * pc[1] + Km[r * 3 + 2] * pc[2];
    float z = fmaxf(pix[2], 1e-5f);
    float u = pix[0] / z, v = pix[1] / z;
    int ok = (pc[2] > 0.f) && (u >= 0.f) && (u < 800.f) && (v >= 0.f) && (v < 448.f);
    refp[(long)idx * 2 + 0] = 2.f * u / 799.f - 1.f;
    refp[(long)idx * 2 + 1] = 2.f * v / 447.f - 1.f;
    valid[idx] = ok;
}

// ---------------- misc elementwise ----------------
__global__ __launch_bounds__(256) void qinit_k(const float* __restrict__ a, const float* __restrict__ b,
                                               float* __restrict__ y)
{
    int i = blockIdx.x * blockDim.x + threadIdx.x;
    if (i >= 2500 * 256) return;
    y[i] = a[i] + b[i];
}

// ---------------- LayerNorm ----------------
__global__ __launch_bounds__(256) void ln_k(const float* __restrict__ x,
                                            const float* __restrict__ g, const float* __restrict__ b,
                                            float* __restrict__ y)
{
    int row  = blockIdx.x * 4 + (threadIdx.x >> 6);
    int lane = threadIdx.x & 63;
    if (row >= 2500) return;
    const float* xp = x + (long)row * 256;
    float v[4];
    #pragma unroll
    for (int i = 0; i < 4; i++) v[i] = xp[lane + 64 * i];
    float s  = v[0] + v[1] + v[2] + v[3];
    float s2 = v[0] * v[0] + v[1] * v[1] + v[2] * v[2] + v[3] * v[3];
    #pragma unroll
    for (int o = 32; o > 0; o >>= 1) { s += __shfl_xor(s, o, 64); s2 += __shfl_xor(s2, o, 64); }
    float mean = s * (1.f / 256.f);
    float var  = s2 * (1.f / 256.f) - mean * mean;
    float rstd = rsqrtf(var + EPS);
    #pragma unroll
    for (int i = 0; i < 4; i++) {
        int cc = lane + 64 * i;
        y[(long)row * 256 + cc] = (v[i] - mean) * rstd * g[cc] + b[cc];
    }
}

// ---------------- MFMA flash-2 MHA with split-K ----------------
__global__ __launch_bounds__(256) void flash2_k(const float* __restrict__ Q,
                                                const float* __restrict__ K,
                                                const float* __restrict__ V,
                                                float* __restrict__ Opart,   // (S,2500,256)
                                                float* __restrict__ MLpart)  // (S,2500,8,2)
{
    const int h  = blockIdx.y;
    const int q0 = blockIdx.x * 64;
    const int sp = blockIdx.z;
    const int kstart = sp * FL_KEYS, kend = kstart + FL_KEYS;
    const int tid = threadIdx.x;
    const int wave = tid >> 6, lane = tid & 63;
    const int quad = lane >> 4, l15 = lane & 15;
    __shared__ __align__(16) short Qs[64 * 40];
    __shared__ __align__(16) short Ks[64 * 40];
    __shared__ __align__(16) short Vt[32 * 72];
    __shared__ __align__(16) short Ps[64 * 72];
    const float scale = 0.17677669529663687f;
    {
        int row = tid >> 2, kc = (tid & 3) << 3;
        int qi = q0 + row;
        short8 pk = {0, 0, 0, 0, 0, 0, 0, 0};
        if (qi < 2500) {
            const float4* qp = (const float4*)(Q + (long)qi * 256 + h * 32 + kc);
            float4 v0 = qp[0], v1 = qp[1];
            pk[0] = f2s(v0.x * scale); pk[1] = f2s(v0.y * scale); pk[2] = f2s(v0.z * scale); pk[3] = f2s(v0.w * scale);
            pk[4] = f2s(v1.x * scale); pk[5] = f2s(v1.y * scale); pk[6] = f2s(v1.z * scale); pk[7] = f2s(v1.w * scale);
        }
        *(short8*)&Qs[row * 40 + kc] = pk;
    }
    __syncthreads();
    short8 aq = *(const short8*)&Qs[(wave * 16 + l15) * 40 + (quad << 3)];
    float m[4], l[4];
    f4 oacc[2];
    #pragma unroll
    for (int r = 0; r < 4; r++) { m[r] = -INFINITY; l[r] = 0.f; }
    oacc[0] = (f4){0.f, 0.f, 0.f, 0.f};
    oacc[1] = (f4){0.f, 0.f, 0.f, 0.f};
    for (int kb = kstart; kb < kend; kb += 64) {
        __syncthreads();
        {
            int row = tid >> 2, kc = (tid & 3) << 3;
            int ki = kb + row;
            short8 pk = {0, 0, 0, 0, 0, 0, 0, 0};
            float vv[8] = {0.f, 0.f, 0.f, 0.f, 0.f, 0.f, 0.f, 0.f};
            if (ki < kend) {
                const float4* kp = (const float4*)(K + (long)ki * 256 + h * 32 + kc);
                float4 a0 = kp[0], a1 = kp[1];
                pk[0] = f2s(a0.x); pk[1] = f2s(a0.y); pk[2] = f2s(a0.z); pk[3] = f2s(a0.w);
                pk[4] = f2s(a1.x); pk[5] = f2s(a1.y); pk[6] = f2s(a1.z); pk[7] = f2s(a1.w);
                const float4* vp = (const float4*)(V + (long)ki * 256 + h * 32 + kc);
                float4 b0 = vp[0], b1 = vp[1];
                vv[0] = b0.x; vv[1] = b0.y; vv[2] = b0.z; vv[3] = b0.w;
                vv[4] = b1.x; vv[5] = b1.y; vv[6] = b1.z; vv[7] = b1.w;
            }
            *(short8*)&Ks[row * 40 + kc] = pk;
            #pragma unroll
            for (int j = 0; j < 8; j++) Vt[(kc + j) * 72 + row] = f2s(vv[j]);
        }
        __syncthreads();
        f4 sa[4];
        #pragma unroll
        for (int ni = 0; ni < 4; ni++) {
            short8 bk = *(const short8*)&Ks[(ni * 16 + l15) * 40 + (quad << 3)];
            sa[ni] = __builtin_amdgcn_mfma_f32_16x16x32_bf16(aq, bk, (f4){0.f, 0.f, 0.f, 0.f}, 0, 0, 0);
        }
        float sv[4][4];
        #pragma unroll
        for (int ni = 0; ni < 4; ni++) {
            bool colok = (kb + ni * 16 + l15) < kend;
            #pragma unroll
            for (int r = 0; r < 4; r++) sv[ni][r] = colok ? sa[ni][r] : -1e30f;
        }
        float p[4][4];
        #pragma unroll
        for (int r = 0; r < 4; r++) {
            float rm = fmaxf(fmaxf(sv[0][r], sv[1][r]), fmaxf(sv[2][r], sv[3][r]));
            #pragma unroll
            for (int off = 1; off < 16; off <<= 1) rm = fmaxf(rm, __shfl_xor(rm, off, 16));
            float mn = fmaxf(m[r], rm);
            float alpha = __expf(m[r] - mn);
            float rs = 0.f;
            #pragma unroll
            for (int ni = 0; ni < 4; ni++) { p[ni][r] = __expf(sv[ni][r] - mn); rs += p[ni][r]; }
            #pragma unroll
            for (int off = 1; off < 16; off <<= 1) rs += __shfl_xor(rs, off, 16);
            l[r] = l[r] * alpha + rs;
            oacc[0][r] *= alpha; oacc[1][r] *= alpha;
            m[r] = mn;
        }
        #pragma unroll
        for (int ni = 0; ni < 4; ni++)
            #pragma unroll
            for (int r = 0; r < 4; r++)
                Ps[(wave * 16 + quad * 4 + r) * 72 + ni * 16 + l15] = f2s(p[ni][r]);
        #pragma unroll
        for (int kh = 0; kh < 2; kh++) {
            short8 ap = *(const short8*)&Ps[(wave * 16 + l15) * 72 + kh * 32 + (quad << 3)];
            #pragma unroll
            for (int ni = 0; ni < 2; ni++) {
                short8 bv = *(const short8*)&Vt[(ni * 16 + l15) * 72 + kh * 32 + (quad << 3)];
                oacc[ni] = __builtin_amdgcn_mfma_f32_16x16x32_bf16(ap, bv, oacc[ni], 0, 0, 0);
            }
        }
    }
    #pragma unroll
    for (int r = 0; r < 4; r++) {
        int qi = q0 + wave * 16 + quad * 4 + r;
        if (qi < 2500) {
            long ob = ((long)sp * 2500 + qi) * 256 + h * 32;
            Opart[ob + l15]      = oacc[0][r];
            Opart[ob + 16 + l15] = oacc[1][r];
            if (l15 == 0) {
                long mb = (((long)sp * 2500 + qi) * 8 + h) * 2;
                MLpart[mb]     = m[r];
                MLpart[mb + 1] = l[r];
            }
        }
    }
}

__global__ __launch_bounds__(256) void flashmerge_k(const float* __restrict__ Opart,
                                                    const float* __restrict__ MLpart,
                                                    float* __restrict__ O)
{
    int q = blockIdx.x, d = threadIdx.x;
    int h = d >> 5;
    float ms[FL_SPLITS], ls[FL_SPLITS];
    float mg = -INFINITY;
    #pragma unroll
    for (int s = 0; s < FL_SPLITS; s++) {
        long mb = (((long)s * 2500 + q) * 8 + h) * 2;
        ms[s] = MLpart[mb];
        ls[s] = MLpart[mb + 1];
        mg = fmaxf(mg, ms[s]);
    }
    float lsum = 0.f, osum = 0.f;
    #pragma unroll
    for (int s = 0; s < FL_SPLITS; s++) {
        float w = __expf(ms[s] - mg);
        lsum += ls[s] * w;
        osum += Opart[((long)s * 2500 + q) * 256 + d] * w;
    }
    O[(long)q * 256 + d] = osum / lsum;
}

// ---------------- masked softmax over 192 deformable-attn logits ----------------
__global__ __launch_bounds__(64) void scasoftmax_k(float* __restrict__ logits, const int* __restrict__ valid)
{
    int q = blockIdx.x, lane = threadIdx.x;
    float v[3]; int mk[3];
    #pragma unroll
    for (int i = 0; i < 3; i++) {
        int idx = i * 64 + lane;
        int c = idx >> 5;
        mk[i] = valid[q * 6 + c];
        v[i] = mk[i] ? logits[(long)q * 192 + idx] : -1e30f;
    }
    float mx = fmaxf(fmaxf(v[0], v[1]), v[2]);
    #pragma unroll
    for (int o = 32; o > 0; o >>= 1) mx = fmaxf(mx, __shfl_xor(mx, o, 64));
    float e[3]; float s = 0.f;
    #pragma unroll
    for (int i = 0; i < 3; i++) { e[i] = expf(v[i] - mx); s += e[i]; }
    #pragma unroll
    for (int o = 32; o > 0; o >>= 1) s += __shfl_xor(s, o, 64);
    float inv = 1.f / s;
    #pragma unroll
    for (int i = 0; i < 3; i++)
        logits[(long)q * 192 + i * 64 + lane] = mk[i] ? e[i] * inv : 0.f;
}

// ---------------- deformable sampling ----------------
__global__ __launch_bounds__(256) void sample_k(const float* __restrict__ vals,
                                                const float* __restrict__ offs,
                                                const float* __restrict__ wts,
                                                const float* __restrict__ refp,
                                                const int* __restrict__ valid,
                                                float* __restrict__ out)
{
    int q = blockIdx.x, d = threadIdx.x;
    __shared__ float s_cw[32][4];
    __shared__ int   s_idx[32][4];
    float acc = 0.f;
    for (int c = 0; c < 6; c++) {
        if (!valid[q * 6 + c]) continue;
        __syncthreads();
        if (d < 32) {
            float ox = offs[(long)q * 384 + (c * 32 + d) * 2 + 0];
            float oy = offs[(long)q * 384 + (c * 32 + d) * 2 + 1];
            float px = refp[(q * 6 + c) * 2 + 0] + ox * (2.f / 49.f);
            float py = refp[(q * 6 + c) * 2 + 1] + oy * (2.f / 27.f);
            float gx = (px + 1.f) * 0.5f * 49.f;
            float gy = (py + 1.f) * 0.5f * 27.f;
            float x0f = floorf(gx), y0f = floorf(gy);
            float wx = gx - x0f, wy = gy - y0f;
            int x0 = (int)x0f, y0 = (int)y0f;
            float wgt = wts[(long)q * 192 + c * 32 + d];
            float cw[4] = {(1.f - wx) * (1.f - wy), wx * (1.f - wy), (1.f - wx) * wy, wx * wy};
            const int dxs[4] = {0, 1, 0, 1};
            const int dys[4] = {0, 0, 1, 1};
            #pragma unroll
            for (int k2 = 0; k2 < 4; k2++) {
                int xi = x0 + dxs[k2], yi = y0 + dys[k2];
                bool ok = (xi >= 0) && (xi < 50) && (yi >= 0) && (yi < 28);
                s_cw[d][k2]  = ok ? cw[k2] * wgt : 0.f;
                s_idx[d][k2] = ok ? (yi * 50 + xi) * 256 : 0;
            }
        }
        __syncthreads();
        const float* vb = vals + (long)c * 358400 + d;
        for (int pt = 0; pt < 32; pt++) {
            #pragma unroll
            for (int k2 = 0; k2 < 4; k2++) {
                float cwv = s_cw[pt][k2];
                if (cwv != 0.f) acc += cwv * vb[s_idx[pt][k2]];
            }
        }
    }
    out[(long)q * 256 + d] = acc;
}

// =====================================================================================
extern "C" void kernel_launch(void* const* d_in, const int* in_sizes, int n_in,
                              void* d_out, int out_size, void* d_ws, size_t ws_size,
                              hipStream_t stream)
{
    const float* images = (const float*)d_in[0];
    const float* intr   = (const float*)d_in[1];
    const float* e2c    = (const float*)d_in[2];
    const float* bevq   = (const float*)d_in[3];
    const float* bevp   = (const float*)d_in[4];
    const float* bbw[5]    = {(const float*)d_in[5],  (const float*)d_in[9],  (const float*)d_in[13], (const float*)d_in[17], (const float*)d_in[21]};
    const float* bbb[5]    = {(const float*)d_in[6],  (const float*)d_in[10], (const float*)d_in[14], (const float*)d_in[18], (const float*)d_in[22]};
    const float* bbg[5]    = {(const float*)d_in[7],  (const float*)d_in[11], (const float*)d_in[15], (const float*)d_in[19], (const float*)d_in[23]};
    const float* bbbeta[5] = {(const float*)d_in[8],  (const float*)d_in[12], (const float*)d_in[16], (const float*)d_in[20], (const float*)d_in[24]};
    const float* sa_wq = (const float*)d_in[25]; const float* sa_bq = (const float*)d_in[26];
    const float* sa_wk = (const float*)d_in[27]; const float* sa_bk = (const float*)d_in[28];
    const float* sa_wv = (const float*)d_in[29]; const float* sa_bv = (const float*)d_in[30];
    const float* sa_wo = (const float*)d_in[31]; const float* sa_bo = (const float*)d_in[32];
    const float* ln1g = (const float*)d_in[33]; const float* ln1b = (const float*)d_in[34];
    const float* ln2g = (const float*)d_in[35]; const float* ln2b = (const float*)d_in[36];
    const float* ln3g = (const float*)d_in[37]; const float* ln3b = (const float*)d_in[38];
    const float* offw = (const float*)d_in[39]; const float* offb = (const float*)d_in[40];
    const float* wtw  = (const float*)d_in[41]; const float* wtb  = (const float*)d_in[42];
    const float* valw = (const float*)d_in[43]; const float* valb = (const float*)d_in[44];
    const float* outw = (const float*)d_in[45]; const float* outb = (const float*)d_in[46];
    const float* fw1  = (const float*)d_in[47]; const float* fb1  = (const float*)d_in[48];
    const float* fw2  = (const float*)d_in[49]; const float* fb2  = (const float*)d_in[50];

    // ---- workspace: ~77.0 MB ----
    float* ws = (float*)d_ws;
    float* bbA   = ws;            ws += 5734400;   // conv0 out / flash Opart (3.2M) + valsb alias
    float* bbB   = ws;            ws += 2867200;   // conv1 out / flash MLpart
    float* feats = ws;            ws += 2150400;   // (6,1400,256) hwd
    float* qbuf  = ws;            ws += 640000;
    float* xq    = ws;            ws += 640000;
    float* bQ    = ws;            ws += 640000;
    float* bK    = ws;            ws += 640000;
    float* bV    = ws;            ws += 640000;
    float* bO    = ws;            ws += 640000;
    float* bH    = ws;            ws += 2560000;   // ffn hidden / offsets / conv3-out (feats3)
    float* bW    = ws;            ws += 480000;    // logits/weights (2500,192)
    float* refp  = ws;            ws += 30016;
    int*   validb = (int*)ws;     ws += 15040;
    float* stats = ws;            ws += 384;       // 6 cams x 32 groups x 2
    float* parts = ws;            ws += 512;       // 32 groups x GN_S x 2
    // aliases
    float* valsb  = bbA + 3200000;
    float* feats3 = bH;
    // bf16 weight buffers
    short* sb = (short*)ws;
    short* cw1b = sb; sb += 73728;
    short* cw2b = sb; sb += 294912;
    short* cw3b = sb; sb += 589824;
    short* cw4b = sb; sb += 65536;
    short* qwT  = sb; sb += 131072;
    short* kwT  = sb; sb += 131072;
    short* vwT  = sb; sb += 131072;
    short* owT  = sb; sb += 131072;
    short* valT = sb; sb += 131072;
    short* outT = sb; sb += 131072;
    short* offT = sb; sb += 196608;
    short* wtT  = sb; sb += 98304;
    short* f1T  = sb; sb += 524288;
    short* f2T  = sb; sb += 524288;

    auto mgemm = [&](const float* A, int lda, const short* Bt, const float* bias, const float* resid,
                     float* C, int M, int N, int K, int act) {
        dim3 g((N + 127) / 128, (M + 127) / 128);
        mgemm_k<<<g, 256, 0, stream>>>(A, lda, Bt, bias, resid, C, M, N, K, act);
    };

    // ---- weight preprocessing ----
    wcast_k<<<(73728 + 255) / 256, 256, 0, stream>>>(bbw[1], cw1b, 73728);
    wcast_k<<<(294912 + 255) / 256, 256, 0, stream>>>(bbw[2], cw2b, 294912);
    wcast_k<<<(589824 + 255) / 256, 256, 0, stream>>>(bbw[3], cw3b, 589824);
    wcast_k<<<(65536 + 255) / 256, 256, 0, stream>>>(bbw[4], cw4b, 65536);
    wtrans_k<<<dim3(4, 4, 2), 256, 0, stream>>>(sa_wq, qwT, 256, 256);
    wtrans_k<<<dim3(4, 4, 2), 256, 0, stream>>>(sa_wk, kwT, 256, 256);
    wtrans_k<<<dim3(4, 4, 2), 256, 0, stream>>>(sa_wv, vwT, 256, 256);
    wtrans_k<<<dim3(4, 4, 2), 256, 0, stream>>>(sa_wo, owT, 256, 256);
    wtrans_k<<<dim3(4, 4, 2), 256, 0, stream>>>(valw, valT, 256, 256);
    wtrans_k<<<dim3(4, 4, 2), 256, 0, stream>>>(outw, outT, 256, 256);
    wtrans_k<<<dim3(6, 4, 2), 256, 0, stream>>>(offw, offT, 256, 384);
    wtrans_k<<<dim3(3, 4, 2), 256, 0, stream>>>(wtw, wtT, 256, 192);
    wtrans_k<<<dim3(16, 4, 2), 256, 0, stream>>>(fw1, f1T, 256, 1024);
    wtrans_k<<<dim3(4, 16, 2), 256, 0, stream>>>(fw2, f2T, 1024, 256);

    // ---- projection of BEV grid ----
    project_k<<<(15000 + 255) / 256, 256, 0, stream>>>(intr, e2c, refp, validb);

    // ---- backbone ----
    for (int c = 0; c < 6; c++) {
        const float* img = images + (long)c * 3 * 448 * 800;
        conv_gemm_k<<<dim3(1400, 1), 256, 0, stream>>>(img, bbw[0], bbb[0], bbA, 3, 64, 448, 800);
        gn_part_k<<<dim3(32, GN_S), 256, 0, stream>>>(bbA, 179200L, parts);
        gn_apply_k<<<22400, 256, 0, stream>>>(bbA, bbg[0], bbbeta[0], parts, 1.f / 179200.f, 89600, 2, 5734400, 1);

        mconv_k<<<dim3(350, 2), 256, 0, stream>>>(bbA, cw1b, bbb[1], bbB, 64, 128, 224, 400, 0);
        gn_part_k<<<dim3(32, GN_S), 256, 0, stream>>>(bbB, 89600L, parts);
        gn_apply_k<<<11200, 256, 0, stream>>>(bbB, bbg[1], bbbeta[1], parts, 1.f / 89600.f, 22400, 4, 2867200, 1);

        mconv_k<<<dim3(88, 4), 256, 0, stream>>>(bbB, cw2b, bbb[2], bbA, 128, 256, 112, 200, 0);
        gn_part_k<<<dim3(32, GN_S), 256, 0, stream>>>(bbA, 44800L, parts);
        gn_apply_k<<<5600, 256, 0, stream>>>(bbA, bbg[2], bbbeta[2], parts, 1.f / 44800.f, 5600, 8, 1433600, 1);

        // conv3 writes spatial-major (1400 x 256) into feats3[c]
        mconv_k<<<dim3(22, 4), 256, 0, stream>>>(bbA, cw3b, bbb[3], feats3 + (long)c * 358400, 256, 256, 56, 100, 1);
    }
    // batched conv3-GN (+relu), conv4 as one 8400x256 GEMM, batched conv4-GN
    gn_stats_hwd_k<<<dim3(32, 6), 256, 0, stream>>>(feats3, stats);
    gn_apply_hwd_k<<<dim3(1400, 6), 256, 0, stream>>>(feats3, bbg[3], bbbeta[3], stats, 1);
    mgemm(feats3, 256, cw4b, bbb[4], nullptr, feats, 8400, 256, 256, 0);
    gn_stats_hwd_k<<<dim3(32, 6), 256, 0, stream>>>(feats, stats);
    gn_apply_hwd_k<<<dim3(1400, 6), 256, 0, stream>>>(feats, bbg[4], bbbeta[4], stats, 0);

    // ---- transformer ----
    qinit_k<<<2500, 256, 0, stream>>>(bevq, bevp, qbuf);

    for (int l = 0; l < 2; l++) {
        long o1 = (long)l * 256;

        // self-attention
        ln_k<<<625, 256, 0, stream>>>(qbuf, ln1g + o1, ln1b + o1, xq);
        mgemm(xq, 256, qwT + l * 65536, sa_bq + o1, nullptr, bQ, 2500, 256, 256, 0);
        mgemm(xq, 256, kwT + l * 65536, sa_bk + o1, nullptr, bK, 2500, 256, 256, 0);
        mgemm(xq, 256, vwT + l * 65536, sa_bv + o1, nullptr, bV, 2500, 256, 256, 0);
        flash2_k<<<dim3(40, 8, FL_SPLITS), 256, 0, stream>>>(bQ, bK, bV, bbA, bbB);
        flashmerge_k<<<2500, 256, 0, stream>>>(bbA, bbB, bO);
        mgemm(bO, 256, owT + l * 65536, sa_bo + o1, qbuf, qbuf, 2500, 256, 256, 0);

        // spatial cross-attention
        ln_k<<<625, 256, 0, stream>>>(qbuf, ln2g + o1, ln2b + o1, xq);
        mgemm(feats, 256, valT + l * 65536, valb + o1, nullptr, valsb, 8400, 256, 256, 0);
        mgemm(xq, 256, offT + l * 98304, offb + (long)l * 384, nullptr, bH, 2500, 384, 256, 0);
        mgemm(xq, 256, wtT + l * 49152, wtb + (long)l * 192, nullptr, bW, 2500, 192, 256, 0);
        scasoftmax_k<<<2500, 64, 0, stream>>>(bW, validb);
        sample_k<<<2500, 256, 0, stream>>>(valsb, bH, bW, refp, validb, bO);
        mgemm(bO, 256, outT + l * 65536, outb + o1, qbuf, qbuf, 2500, 256, 256, 0);

        // FFN
        ln_k<<<625, 256, 0, stream>>>(qbuf, ln3g + o1, ln3b + o1, xq);
        mgemm(xq, 256, f1T + l * 262144, fb1 + (long)l * 1024, nullptr, bH, 2500, 1024, 256, 2);
        mgemm(bH, 1024, f2T + l * 262144, fb2 + o1, qbuf,
              (l == 1) ? (float*)d_out : qbuf, 2500, 256, 1024, 0);
    }
}